// Round 2
// baseline (640.688 us; speedup 1.0000x reference)
//
#include <hip/hip_runtime.h>

// RESCAL bilinear: pos = h^T R t, neg = nh^T R nt, R in {200} x [128x128] fp32.
// Single kernel. Each block owns (relation r, index-range j): scans rel[] slice
// (16 KB, L2-shared across the 200 same-j blocks), ballot-compacts its matching
// triples (no atomics, no workspace), stages R via global_load_lds with
// pre-swizzled source (XOR involution -> conflict-free b128 row reads), then
// vector-FMA u = R*t (lane owns rows d=lane, lane+64) and butterfly-reduces
// h.u. fp32 has no MFMA on CDNA4 -> VALU-bound, ~7.3 us pure-issue floor.

#define NB    16384
#define D     128
#define NREL  200
#define SPLIT 4
#define RANGE (NB/SPLIT)          // 4096 triples scanned per block
#define NT    4                   // triples per wave-group
#define TV    (2*NT)              // t-vectors (t + nt) per wave-group

typedef const __attribute__((address_space(1))) char gchar;
typedef __attribute__((address_space(3))) char       lchar;

__device__ __forceinline__ void gload_lds16(const void* g, void* l) {
    // async global->LDS DMA, 16 B/lane, dest = wave-uniform base + lane*16
    __builtin_amdgcn_global_load_lds((gchar*)g, (lchar*)l, 16, 0, 0);
}

__global__ __launch_bounds__(256, 2) void rescal_score(
    const int* __restrict__ heads, const int* __restrict__ tails,
    const int* __restrict__ nheads, const int* __restrict__ ntails,
    const int* __restrict__ rel, const float* __restrict__ ent,
    const float* __restrict__ relm, float* __restrict__ out)
{
    __shared__ __align__(16) float Rlds[D * D];        // 64 KB, swizzled
    __shared__ __align__(16) float tlds[4][TV][64];    // 8 KB: half-D per stage
    __shared__ int list[4][64];                        // per-wave match lists
    __shared__ int wcnt[4];

    const int tid  = threadIdx.x;
    const int wave = tid >> 6;
    const int lane = tid & 63;
    const int r = blockIdx.x % NREL;   // 200%8==0 -> all j-blocks of r on one XCD
    const int j = blockIdx.x / NREL;

    // ---- issue R -> LDS: linear dest, source pre-swizzled (XOR involution) ----
    const char* Rg = (const char*)(relm + (size_t)r * (D * D));
    char* Rb = (char*)Rlds;
    #pragma unroll
    for (int k = 0; k < 16; ++k) {
        unsigned dst = (unsigned)k * 4096u + (unsigned)wave * 1024u;
        unsigned lin = dst + (unsigned)lane * 16u;
        unsigned src = lin ^ (((lin >> 9) & 7u) << 4);  // LDS[y] = G[swz(y)]
        gload_lds16(Rg + src, Rb + dst);
    }

    // ---- scan my rel[] sub-slice; per-wave ordered ballot compaction ----
    {
        const int base = j * RANGE + wave * (RANGE / 4);
        int tot = 0;
        #pragma unroll
        for (int rd = 0; rd < (RANGE / 4) / 64; ++rd) {   // 16 rounds
            int i = base + rd * 64 + lane;
            bool m = (rel[i] == r);
            unsigned long long mask = __ballot(m);
            if (m) {
                int pos = tot + __popcll(mask & ((1ull << lane) - 1ull));
                if (pos < 64) list[wave][pos] = i;
            }
            tot += __popcll(mask);
        }
        if (lane == 0) wcnt[wave] = (tot < 64) ? tot : 64;
    }
    __syncthreads();   // drains R staging (vmcnt) + publishes list/wcnt

    const int c0 = wcnt[0], c1 = wcnt[1], c2 = wcnt[2], c3 = wcnt[3];
    const int cnt = c0 + c1 + c2 + c3;

    const unsigned xsw  = ((unsigned)(lane & 7)) << 4;
    const unsigned rowA = (unsigned)lane * 512u;           // row d = lane
    const unsigned rowB = (unsigned)(lane + 64) * 512u;    // row d = lane+64

    // per-lane t-stage geometry: op o covers vectors v = o*4 + (lane>>4);
    // dest float idx = lane*4 = v*64 + (lane&15)*4  == tlds[wave][v][..]
    const int vA = lane >> 4;                // 0..3
    const int fo = (lane & 15) * 4;          // float offset within 64-col half

    for (int s0 = wave * NT; s0 < cnt; s0 += 4 * NT) {
        // resolve triple ids from the 4 per-wave segments
        int trip[NT];
        #pragma unroll
        for (int q = 0; q < NT; ++q) {
            int s = s0 + q; if (s >= cnt) s = cnt - 1;   // clamp; store guarded
            int a = s, seg = 0;
            if (a >= c0) { a -= c0; seg = 1;
              if (a >= c1) { a -= c1; seg = 2;
                if (a >= c2) { a -= c2; seg = 3; } } }
            trip[q] = list[seg][a];
        }

        // t-row base addresses for this lane's staging vectors (v and v+4)
        const int* selT = (vA & 1) ? ntails : tails;
        const float* srcA = ent + (size_t)selT[trip[vA >> 1]]       * D + fo;
        const float* srcB = ent + (size_t)selT[trip[2 + (vA >> 1)]] * D + fo;

        // ---- stage t half 0 (cols 0..63) ----
        asm volatile("s_waitcnt lgkmcnt(0)" ::: "memory"); // prior reads drained
        gload_lds16(srcA,      &tlds[wave][0][0]);
        gload_lds16(srcB,      &tlds[wave][4][0]);

        // h rows: lane keeps d=lane and d=lane+64 (coalesced dword loads)
        float h0[TV], h1[TV];
        #pragma unroll
        for (int v = 0; v < TV; ++v) {
            const int* sel = (v & 1) ? nheads : heads;
            const float* hrow = ent + (size_t)sel[trip[v >> 1]] * D;
            h0[v] = hrow[lane];
            h1[v] = hrow[lane + 64];
        }

        float acc0[TV], acc1[TV];
        #pragma unroll
        for (int v = 0; v < TV; ++v) { acc0[v] = 0.f; acc1[v] = 0.f; }

        asm volatile("s_waitcnt vmcnt(0)" ::: "memory");   // t half 0 landed

        #pragma unroll 4
        for (int e0 = 0; e0 < 64; e0 += 4) {
            float4 ra = *(const float4*)(Rb + ((rowA + e0 * 4) ^ xsw));
            float4 rb = *(const float4*)(Rb + ((rowB + e0 * 4) ^ xsw));
            #pragma unroll
            for (int v = 0; v < TV; ++v) {
                float4 t4 = *(const float4*)(&tlds[wave][v][e0]);
                acc0[v] += ra.x * t4.x + ra.y * t4.y + ra.z * t4.z + ra.w * t4.w;
                acc1[v] += rb.x * t4.x + rb.y * t4.y + rb.z * t4.z + rb.w * t4.w;
            }
        }

        // ---- stage t half 1 (cols 64..127) into the same 8 KB buffer ----
        asm volatile("s_waitcnt lgkmcnt(0)" ::: "memory"); // half-0 reads drained
        gload_lds16(srcA + 64, &tlds[wave][0][0]);
        gload_lds16(srcB + 64, &tlds[wave][4][0]);
        asm volatile("s_waitcnt vmcnt(0)" ::: "memory");   // t half 1 landed

        #pragma unroll 4
        for (int e0 = 0; e0 < 64; e0 += 4) {
            float4 ra = *(const float4*)(Rb + ((rowA + 256 + e0 * 4) ^ xsw));
            float4 rb = *(const float4*)(Rb + ((rowB + 256 + e0 * 4) ^ xsw));
            #pragma unroll
            for (int v = 0; v < TV; ++v) {
                float4 t4 = *(const float4*)(&tlds[wave][v][e0]);
                acc0[v] += ra.x * t4.x + ra.y * t4.y + ra.z * t4.z + ra.w * t4.w;
                acc1[v] += rb.x * t4.x + rb.y * t4.y + rb.z * t4.z + rb.w * t4.w;
            }
        }

        // ---- score = sum_d h[d]*u[d]; 64-lane butterfly; lane0 stores ----
        #pragma unroll
        for (int v = 0; v < TV; ++v) {
            float p = h0[v] * acc0[v] + h1[v] * acc1[v];
            #pragma unroll
            for (int m = 32; m >= 1; m >>= 1) p += __shfl_xor(p, m, 64);
            if (lane == 0) {
                int s = s0 + (v >> 1);
                if (s < cnt) {
                    float* o = (v & 1) ? (out + NB) : out;
                    o[trip[v >> 1]] = p;
                }
            }
        }
    }
}

extern "C" void kernel_launch(void* const* d_in, const int* in_sizes, int n_in,
                              void* d_out, int out_size, void* d_ws, size_t ws_size,
                              hipStream_t stream)
{
    const int*   heads  = (const int*)d_in[0];
    const int*   tails  = (const int*)d_in[1];
    const int*   nheads = (const int*)d_in[2];
    const int*   ntails = (const int*)d_in[3];
    const int*   rels   = (const int*)d_in[4];
    const float* ent    = (const float*)d_in[5];
    const float* relm   = (const float*)d_in[6];
    float* out = (float*)d_out;

    rescal_score<<<NREL * SPLIT, 256, 0, stream>>>(heads, tails, nheads, ntails,
                                                   rels, ent, relm, out);
}